// Round 17
// baseline (270.194 us; speedup 1.0000x reference)
//
#include <hip/hip_runtime.h>
#include <hip/hip_bf16.h>

#define B_    4
#define S_    512
#define NS_   8192
#define MAXW  16
#define H_    256
#define NH_   4
#define FF_   1024
#define NSPAN (B_*NS_)
#define NEGV  (-1.0e9f)
#define MT    64
#define LDSK  264

typedef short s16x8 __attribute__((ext_vector_type(8)));
typedef float f32x4 __attribute__((ext_vector_type(4)));

__device__ __forceinline__ unsigned short f2bu(float v){
  __hip_bfloat16 h = __float2bfloat16(v);
  union { __hip_bfloat16 h; unsigned short u; } c; c.h = h; return c.u;
}
__device__ __forceinline__ float bu2f(unsigned short u){
  union { unsigned int i; float f; } c; c.i = ((unsigned int)u) << 16; return c.f;
}
__device__ __forceinline__ f32x4 MFMA(s16x8 a, s16x8 b, f32x4 c){
  return __builtin_amdgcn_mfma_f32_16x16x32_bf16(a, b, c, 0, 0, 0);
}

// ---- prep_q: 4 blocks (one per head), thread-parallel q ----
__global__ __launch_bounds__(256) void prep_q_kernel(
    const float* __restrict__ dq, const float* __restrict__ wq,
    const float* __restrict__ wk, const float* __restrict__ bqkv,
    float* __restrict__ qkvec, float* __restrict__ qb)
{
  __shared__ float q_s[H_];
  const int t = threadIdx.x;
  const int h = blockIdx.x;
  float acc = bqkv[t];
  const float4* wr = (const float4*)(wq + (size_t)t*H_);
  #pragma unroll 8
  for (int c = 0; c < 64; ++c) {
    float4 u = wr[c];
    float4 d = *(const float4*)(dq + c*4);
    acc += u.x*d.x + u.y*d.y + u.z*d.z + u.w*d.w;
  }
  q_s[t] = acc;
  __syncthreads();
  float s = 0.f;
  #pragma unroll 8
  for (int d = 0; d < 64; ++d) s += q_s[h*64 + d] * wk[(size_t)(h*64 + d)*H_ + t];
  qkvec[h*H_ + t] = s;
  if (t < 64) {
    float p = q_s[h*64 + t] * bqkv[H_ + h*64 + t];
    #pragma unroll
    for (int off = 32; off; off >>= 1) p += __shfl_down(p, off);
    if (t == 0) qb[h] = p;
  }
}

// ---- prep_all: [0,2048) trbf+logits; [2048,3072) W1T; [3072,4096) W2T;
//                [4096,4352) Wcomb; 4352 zbias ----
__global__ __launch_bounds__(256) void prep_all_kernel(
    const float* __restrict__ tok, const float* __restrict__ qkvec,
    const float* __restrict__ qb,
    const float* __restrict__ wv, const float* __restrict__ wo,
    const float* __restrict__ bqkv, const float* __restrict__ bo,
    const float* __restrict__ dq,
    const float* __restrict__ w1, const float* __restrict__ w2,
    unsigned short* __restrict__ trbf,
    float* __restrict__ lt, unsigned short* __restrict__ wct,
    unsigned short* __restrict__ w1t, unsigned short* __restrict__ w2t,
    float* __restrict__ zbias)
{
  const int blk = blockIdx.x;
  const int t = threadIdx.x;
  if (blk < 2048) {
    __shared__ float red[4][4];
    const int row = blk;
    const int p = row & (S_ - 1);
    float fac = expf((float)((t >> 1)*2) * (-9.210340371976184f / 256.0f));
    float ang = (float)p * fac;
    float pe = (t & 1) ? cosf(ang) : sinf(ang);
    float v = tok[(size_t)row*H_ + t] + pe;
    trbf[(size_t)row*H_ + t] = f2bu(v);
    float p0 = qkvec[t]*v, p1 = qkvec[H_+t]*v, p2 = qkvec[2*H_+t]*v, p3 = qkvec[3*H_+t]*v;
    const int l = t & 63, wv_ = t >> 6;
    #pragma unroll
    for (int m = 1; m < 64; m <<= 1) {
      p0 += __shfl_xor(p0, m); p1 += __shfl_xor(p1, m);
      p2 += __shfl_xor(p2, m); p3 += __shfl_xor(p3, m);
    }
    if (l == 0) { red[wv_][0]=p0; red[wv_][1]=p1; red[wv_][2]=p2; red[wv_][3]=p3; }
    __syncthreads();
    if (t < 4)
      lt[row*NH_ + t] = (red[0][t]+red[1][t]+red[2][t]+red[3][t] + qb[t]) * 0.125f;
  } else if (blk < 3072) {
    int idx = (blk - 2048)*256 + t;
    int n = idx >> 8, k = idx & 255;
    w1t[idx] = f2bu(w1[(size_t)k*FF_ + n]);
  } else if (blk < 4096) {
    int idx = (blk - 3072)*256 + t;
    int n = idx >> 10, k = idx & 1023;
    w2t[idx] = f2bu(w2[(size_t)k*H_ + n]);
  } else if (blk < 4352) {
    __shared__ float wo_s[H_];
    const int i = blk - 4096;
    wo_s[t] = wo[(size_t)i*H_ + t];
    __syncthreads();
    #pragma unroll
    for (int h = 0; h < NH_; ++h) {
      float s = 0.f;
      #pragma unroll 8
      for (int d = 0; d < 64; ++d)
        s += wo_s[h*64 + d] * wv[(size_t)(h*64 + d)*H_ + t];
      wct[(size_t)i*1024 + h*H_ + t] = f2bu(s);
    }
  } else {
    __shared__ float bv_s[H_];
    bv_s[t] = bqkv[2*H_ + t];
    __syncthreads();
    float acc = bo[t] + dq[t];
    const float4* wr = (const float4*)(wo + (size_t)t*H_);
    #pragma unroll 8
    for (int c = 0; c < 64; ++c) {
      float4 u = wr[c];
      acc += u.x*bv_s[c*4] + u.y*bv_s[c*4+1] + u.z*bv_s[c*4+2] + u.w*bv_s[c*4+3];
    }
    zbias[t] = acc;
  }
}

// ---- K=256 GEMM step (r7/r15, no-spill): A in LDS (stride LDSK), nf=2 mf=4 ----
__device__ __forceinline__ void gemm8(const unsigned short* __restrict__ As,
                                      const unsigned short* __restrict__ bp0,
                                      const unsigned short* __restrict__ bp1,
                                      f32x4 (&ac)[4][2], int ln16, int lg)
{
  s16x8 B0 = *(const s16x8*)bp0;
  s16x8 B1 = *(const s16x8*)bp1;
  #pragma unroll
  for (int s = 0; s < 8; ++s) {
    s16x8 N0 = B0, N1 = B1;
    if (s < 7) { N0 = *(const s16x8*)(bp0 + (s+1)*32); N1 = *(const s16x8*)(bp1 + (s+1)*32); }
    s16x8 a0 = *(const s16x8*)(As + (0*16+ln16)*LDSK + s*32 + lg*8);
    s16x8 a1 = *(const s16x8*)(As + (1*16+ln16)*LDSK + s*32 + lg*8);
    s16x8 a2 = *(const s16x8*)(As + (2*16+ln16)*LDSK + s*32 + lg*8);
    s16x8 a3 = *(const s16x8*)(As + (3*16+ln16)*LDSK + s*32 + lg*8);
    ac[0][0]=MFMA(a0,B0,ac[0][0]); ac[1][0]=MFMA(a1,B0,ac[1][0]);
    ac[2][0]=MFMA(a2,B0,ac[2][0]); ac[3][0]=MFMA(a3,B0,ac[3][0]);
    ac[0][1]=MFMA(a0,B1,ac[0][1]); ac[1][1]=MFMA(a1,B1,ac[1][1]);
    ac[2][1]=MFMA(a2,B1,ac[2][1]); ac[3][1]=MFMA(a3,B1,ac[3][1]);
    B0 = N0; B1 = N1;
  }
}

// ---- fused v6: in-kernel attn+pool (r13 mapping) -> Z GEMM -> LN1 -> FFN -> LN2 ----
__global__ __launch_bounds__(512, 4) void fused_gemm_kernel(
    const unsigned short* __restrict__ trbf, const float* __restrict__ lt,
    const int* __restrict__ span_ids, const int* __restrict__ span_masks,
    const unsigned short* __restrict__ wct, const float* __restrict__ zbias,
    const unsigned short* __restrict__ w1t, const float* __restrict__ b1,
    const unsigned short* __restrict__ w2t, const float* __restrict__ b2,
    const float* __restrict__ lng, const float* __restrict__ lnb,
    float* __restrict__ out)
{
  __shared__ __align__(16) unsigned short bufA[MT*LDSK];  // head-even / f1
  __shared__ __align__(16) unsigned short bufB[MT*LDSK];  // head-odd / y
  __shared__ __align__(16) float scratch[2048];           // attn (pool) / part_s (LN)
  __shared__ int meta_rb[MT];
  __shared__ int meta_len[MT];
  __shared__ int meta_mk[MT];

  float (*attn_s)[MT][16] = (float(*)[MT][16])scratch;    // [2][64][16]
  float (*part_s)[MT][2]  = (float(*)[MT][2])scratch;     // [8][64][2]

  const int t = threadIdx.x;            // 0..511
  const int l = t & 63;
  const int w = t >> 6;                 // wave 0..7
  const int ln16 = l & 15;
  const int lg = l >> 4;
  const int m0 = blockIdx.x * MT;
  const int ncol = w * 32;

  if (t < MT) {
    int gs = m0 + t;
    int st = span_ids[gs*2];
    int en = span_ids[gs*2 + 1];
    int mk = span_masks[gs];
    meta_rb[t]  = (gs >> 13) * S_ + st;
    meta_len[t] = mk ? (en - st) : 0;
    meta_mk[t]  = mk;
  }
  __syncthreads();

  auto attn_pass = [&](int p){
    #pragma unroll
    for (int q = 0; q < 4; ++q) {
      int slot = q*512 + t;            // 0..2047
      int w16 = slot & 15;
      int sp  = (slot >> 4) & 63;
      int h2  = slot >> 10;            // 0/1
      int rb  = meta_rb[sp];
      int len = meta_len[sp];
      float lg_ = (w16 < len) ? lt[(rb + w16)*NH_ + p*2 + h2] : NEGV;
      float mx = lg_;
      mx = fmaxf(mx, __shfl_xor(mx,1));
      mx = fmaxf(mx, __shfl_xor(mx,2));
      mx = fmaxf(mx, __shfl_xor(mx,4));
      mx = fmaxf(mx, __shfl_xor(mx,8));
      float e = expf(lg_ - mx);
      float se = e;
      se += __shfl_xor(se,1); se += __shfl_xor(se,2);
      se += __shfl_xor(se,4); se += __shfl_xor(se,8);
      attn_s[h2][sp][w16] = e / se;
    }
  };

  auto pool_pass = [&](){
    #pragma unroll 1
    for (int i = 0; i < 8; ++i) {
      int sp = w*8 + i;
      int rb = meta_rb[sp];
      const ushort4* p4 = (const ushort4*)(trbf + (size_t)rb*H_) + l;
      float a0=0,a1=0,a2=0,a3=0, q0=0,q1=0,q2=0,q3=0;
      #pragma unroll
      for (int w2 = 0; w2 < MAXW; ++w2) {
        ushort4 xv = p4[w2*64];
        float av0 = attn_s[0][sp][w2];
        float av1 = attn_s[1][sp][w2];
        float x0=bu2f(xv.x), x1=bu2f(xv.y), x2=bu2f(xv.z), x3=bu2f(xv.w);
        a0 += av0*x0; a1 += av0*x1; a2 += av0*x2; a3 += av0*x3;
        q0 += av1*x0; q1 += av1*x1; q2 += av1*x2; q3 += av1*x3;
      }
      ushort4 o0, o1;
      o0.x=f2bu(a0); o0.y=f2bu(a1); o0.z=f2bu(a2); o0.w=f2bu(a3);
      o1.x=f2bu(q0); o1.y=f2bu(q1); o1.z=f2bu(q2); o1.w=f2bu(q3);
      *(ushort4*)(bufA + sp*LDSK + l*4) = o0;
      *(ushort4*)(bufB + sp*LDSK + l*4) = o1;
    }
  };

  const int col0 = ncol + ln16, col1 = ncol + 16 + ln16;

  // ---- attn + pool + Z GEMM (K = 4 heads x 256) ----
  f32x4 acc[4][2];
  #pragma unroll
  for (int mf = 0; mf < 4; ++mf){ acc[mf][0]=(f32x4){0,0,0,0}; acc[mf][1]=(f32x4){0,0,0,0}; }

  attn_pass(0);
  __syncthreads();
  pool_pass();                       // heads 0,1 -> bufA, bufB
  __syncthreads();
  attn_pass(1);                      // heads 2,3 (attn_s readers done)
  gemm8(bufA, wct + (size_t)col0*1024 + 0*256 + lg*8,
               wct + (size_t)col1*1024 + 0*256 + lg*8, acc, ln16, lg);
  gemm8(bufB, wct + (size_t)col0*1024 + 1*256 + lg*8,
               wct + (size_t)col1*1024 + 1*256 + lg*8, acc, ln16, lg);
  __syncthreads();                   // gemm reads + attn writes done
  pool_pass();                       // heads 2,3 -> bufA, bufB
  __syncthreads();
  gemm8(bufA, wct + (size_t)col0*1024 + 2*256 + lg*8,
               wct + (size_t)col1*1024 + 2*256 + lg*8, acc, ln16, lg);
  gemm8(bufB, wct + (size_t)col0*1024 + 3*256 + lg*8,
               wct + (size_t)col1*1024 + 3*256 + lg*8, acc, ln16, lg);

  // ---- + zbias, LN1 -> y into bufB ----
  unsigned short* y_s  = bufB;
  unsigned short* f1_s = bufA;
  {
    const float zb0 = zbias[col0], zb1 = zbias[col1];
    const float g0  = lng[col0],   g1  = lng[col1];
    const float bl0 = lnb[col0],   bl1 = lnb[col1];
    float vals[4][4][2];
    #pragma unroll
    for (int mf = 0; mf < 4; ++mf)
      #pragma unroll
      for (int r = 0; r < 4; ++r) {
        const int row = mf*16 + lg*4 + r;
        float v0 = acc[mf][0][r] + zb0;
        float v1 = acc[mf][1][r] + zb1;
        vals[mf][r][0] = v0; vals[mf][r][1] = v1;
        float s1 = v0 + v1, s2 = v0*v0 + v1*v1;
        s1 += __shfl_xor(s1,1); s2 += __shfl_xor(s2,1);
        s1 += __shfl_xor(s1,2); s2 += __shfl_xor(s2,2);
        s1 += __shfl_xor(s1,4); s2 += __shfl_xor(s2,4);
        s1 += __shfl_xor(s1,8); s2 += __shfl_xor(s2,8);
        if (ln16 == 0) { part_s[w][row][0] = s1; part_s[w][row][1] = s2; }
      }
    __syncthreads();                 // also: all gemm8 reads of bufB done
    #pragma unroll
    for (int mf = 0; mf < 4; ++mf)
      #pragma unroll
      for (int r = 0; r < 4; ++r) {
        const int row = mf*16 + lg*4 + r;
        float s1 = 0.f, s2 = 0.f;
        #pragma unroll
        for (int j = 0; j < 8; ++j) { s1 += part_s[j][row][0]; s2 += part_s[j][row][1]; }
        float mean = s1 * (1.f/H_);
        float var  = s2 * (1.f/H_) - mean*mean; var = fmaxf(var, 0.f);
        float rstd = rsqrtf(var + 1e-5f);
        y_s[row*LDSK + col0] = f2bu((vals[mf][r][0]-mean)*rstd*g0 + bl0);
        y_s[row*LDSK + col1] = f2bu((vals[mf][r][1]-mean)*rstd*g1 + bl1);
      }
  }
  __syncthreads();

  // ---- FFN ----
  f32x4 f2acc[4][2];
  #pragma unroll
  for (int mf = 0; mf < 4; ++mf){ f2acc[mf][0]=(f32x4){0,0,0,0}; f2acc[mf][1]=(f32x4){0,0,0,0}; }

  #pragma unroll 1
  for (int nc = 0; nc < 4; ++nc) {
    #pragma unroll
    for (int mf = 0; mf < 4; ++mf){ acc[mf][0]=(f32x4){0,0,0,0}; acc[mf][1]=(f32x4){0,0,0,0}; }
    const unsigned short* b10 = w1t + (size_t)(nc*256 + col0)*256 + lg*8;
    const unsigned short* b11 = w1t + (size_t)(nc*256 + col1)*256 + lg*8;
    gemm8(y_s, b10, b11, acc, ln16, lg);
    __syncthreads();   // prior FFN2 readers of f1_s done
    {
      const float bb0 = b1[nc*256 + col0];
      const float bb1 = b1[nc*256 + col1];
      #pragma unroll
      for (int mf = 0; mf < 4; ++mf)
        #pragma unroll
        for (int r = 0; r < 4; ++r) {
          const int row = mf*16 + lg*4 + r;
          f1_s[row*LDSK + col0] = f2bu(fmaxf(acc[mf][0][r] + bb0, 0.f));
          f1_s[row*LDSK + col1] = f2bu(fmaxf(acc[mf][1][r] + bb1, 0.f));
        }
    }
    __syncthreads();
    const unsigned short* b20 = w2t + (size_t)col0*1024 + nc*256 + lg*8;
    const unsigned short* b21 = w2t + (size_t)col1*1024 + nc*256 + lg*8;
    gemm8(f1_s, b20, b21, f2acc, ln16, lg);
  }

  // ---- epilogue: +b2 +resid(y), LN2, mask, store ----
  {
    const float b20v = b2[col0],  b21v = b2[col1];
    const float g0   = lng[col0], g1   = lng[col1];
    const float bl0  = lnb[col0], bl1  = lnb[col1];
    float vals[4][4][2];
    #pragma unroll
    for (int mf = 0; mf < 4; ++mf)
      #pragma unroll
      for (int r = 0; r < 4; ++r) {
        const int row = mf*16 + lg*4 + r;
        float v0 = f2acc[mf][0][r] + b20v + bu2f(y_s[row*LDSK + col0]);
        float v1 = f2acc[mf][1][r] + b21v + bu2f(y_s[row*LDSK + col1]);
        vals[mf][r][0] = v0; vals[mf][r][1] = v1;
        float s1 = v0 + v1, s2 = v0*v0 + v1*v1;
        s1 += __shfl_xor(s1,1); s2 += __shfl_xor(s2,1);
        s1 += __shfl_xor(s1,2); s2 += __shfl_xor(s2,2);
        s1 += __shfl_xor(s1,4); s2 += __shfl_xor(s2,4);
        s1 += __shfl_xor(s1,8); s2 += __shfl_xor(s2,8);
        if (ln16 == 0) { part_s[w][row][0] = s1; part_s[w][row][1] = s2; }
      }
    __syncthreads();
    #pragma unroll
    for (int mf = 0; mf < 4; ++mf)
      #pragma unroll
      for (int r = 0; r < 4; ++r) {
        const int row = mf*16 + lg*4 + r;
        const int span = m0 + row;
        float s1 = 0.f, s2 = 0.f;
        #pragma unroll
        for (int j = 0; j < 8; ++j) { s1 += part_s[j][row][0]; s2 += part_s[j][row][1]; }
        float mean = s1 * (1.f/H_);
        float var  = s2 * (1.f/H_) - mean*mean; var = fmaxf(var, 0.f);
        float rstd = rsqrtf(var + 1e-5f);
        int mk = meta_mk[row];
        float o0 = (vals[mf][r][0]-mean)*rstd*g0 + bl0;
        float o1 = (vals[mf][r][1]-mean)*rstd*g1 + bl1;
        out[(size_t)span*H_ + col0] = mk ? o0 : 0.f;
        out[(size_t)span*H_ + col1] = mk ? o1 : 0.f;
      }
  }
}

extern "C" void kernel_launch(void* const* d_in, const int* in_sizes, int n_in,
                              void* d_out, int out_size, void* d_ws, size_t ws_size,
                              hipStream_t stream) {
  const float* tok      = (const float*)d_in[0];
  const int* span_ids   = (const int*)d_in[1];
  const int* span_masks = (const int*)d_in[2];
  const float* dq   = (const float*)d_in[4];
  const float* wq   = (const float*)d_in[5];
  const float* wk   = (const float*)d_in[6];
  const float* wv   = (const float*)d_in[7];
  const float* bqkv = (const float*)d_in[8];
  const float* wo   = (const float*)d_in[9];
  const float* bo   = (const float*)d_in[10];
  const float* lng  = (const float*)d_in[11];
  const float* lnb  = (const float*)d_in[12];
  const float* w1   = (const float*)d_in[13];
  const float* b1   = (const float*)d_in[14];
  const float* w2   = (const float*)d_in[15];
  const float* b2   = (const float*)d_in[16];

  float* ws    = (float*)d_ws;
  float* qkvec = ws;                         // 1024 f
  float* qbuf  = qkvec + 1024;               // 8 f
  float* lt    = qbuf + 8;                   // 8192 f
  float* zbias = lt + 8192;                  // 256 f
  unsigned short* ub = (unsigned short*)(zbias + 256);
  unsigned short* trbf = ub;                 // 524288
  unsigned short* wct  = trbf + 524288;      // 262144
  unsigned short* w1t  = wct + 262144;       // 262144
  unsigned short* w2t  = w1t + 262144;       // 262144

  hipLaunchKernelGGL(prep_q_kernel, dim3(NH_), dim3(256), 0, stream,
                     dq, wq, wk, bqkv, qkvec, qbuf);
  hipLaunchKernelGGL(prep_all_kernel, dim3(4353), dim3(256), 0, stream,
                     tok, qkvec, qbuf, wv, wo, bqkv, bo, dq, w1, w2,
                     trbf, lt, wct, w1t, w2t, zbias);
  hipLaunchKernelGGL(fused_gemm_kernel, dim3(NSPAN/MT), dim3(512), 0, stream,
                     trbf, lt, span_ids, span_masks, wct, zbias,
                     w1t, b1, w2t, b2, lng, lnb, (float*)d_out);
}

// Round 18
// 175.605 us; speedup vs baseline: 1.5386x; 1.5386x over previous
//
#include <hip/hip_runtime.h>
#include <hip/hip_bf16.h>

#define B_    4
#define S_    512
#define NS_   8192
#define MAXW  16
#define H_    256
#define NH_   4
#define FF_   1024
#define NSPAN (B_*NS_)
#define NEGV  (-1.0e9f)
#define MT    64
#define LDSK  264

typedef short s16x8 __attribute__((ext_vector_type(8)));
typedef float f32x4 __attribute__((ext_vector_type(4)));

__device__ __forceinline__ unsigned short f2bu(float v){
  __hip_bfloat16 h = __float2bfloat16(v);
  union { __hip_bfloat16 h; unsigned short u; } c; c.h = h; return c.u;
}
__device__ __forceinline__ float bu2f(unsigned short u){
  union { unsigned int i; float f; } c; c.i = ((unsigned int)u) << 16; return c.f;
}
__device__ __forceinline__ f32x4 MFMA(s16x8 a, s16x8 b, f32x4 c){
  return __builtin_amdgcn_mfma_f32_16x16x32_bf16(a, b, c, 0, 0, 0);
}

// ---- prep_q: 4 blocks (one per head), thread-parallel q ----
__global__ __launch_bounds__(256) void prep_q_kernel(
    const float* __restrict__ dq, const float* __restrict__ wq,
    const float* __restrict__ wk, const float* __restrict__ bqkv,
    float* __restrict__ qkvec, float* __restrict__ qb)
{
  __shared__ float q_s[H_];
  const int t = threadIdx.x;
  const int h = blockIdx.x;
  float acc = bqkv[t];
  const float4* wr = (const float4*)(wq + (size_t)t*H_);
  #pragma unroll 8
  for (int c = 0; c < 64; ++c) {
    float4 u = wr[c];
    float4 d = *(const float4*)(dq + c*4);
    acc += u.x*d.x + u.y*d.y + u.z*d.z + u.w*d.w;
  }
  q_s[t] = acc;
  __syncthreads();
  float s = 0.f;
  #pragma unroll 8
  for (int d = 0; d < 64; ++d) s += q_s[h*64 + d] * wk[(size_t)(h*64 + d)*H_ + t];
  qkvec[h*H_ + t] = s;
  if (t < 64) {
    float p = q_s[h*64 + t] * bqkv[H_ + h*64 + t];
    #pragma unroll
    for (int off = 32; off; off >>= 1) p += __shfl_down(p, off);
    if (t == 0) qb[h] = p;
  }
}

// ---- prep_all: [0,2048) trbf+logits; [2048,3072) W1T; [3072,4096) W2T;
//                [4096,4352) Wcomb; 4352 zbias ----
__global__ __launch_bounds__(256) void prep_all_kernel(
    const float* __restrict__ tok, const float* __restrict__ qkvec,
    const float* __restrict__ qb,
    const float* __restrict__ wv, const float* __restrict__ wo,
    const float* __restrict__ bqkv, const float* __restrict__ bo,
    const float* __restrict__ dq,
    const float* __restrict__ w1, const float* __restrict__ w2,
    unsigned short* __restrict__ trbf,
    float* __restrict__ lt, unsigned short* __restrict__ wct,
    unsigned short* __restrict__ w1t, unsigned short* __restrict__ w2t,
    float* __restrict__ zbias)
{
  const int blk = blockIdx.x;
  const int t = threadIdx.x;
  if (blk < 2048) {
    __shared__ float red[4][4];
    const int row = blk;
    const int p = row & (S_ - 1);
    float fac = expf((float)((t >> 1)*2) * (-9.210340371976184f / 256.0f));
    float ang = (float)p * fac;
    float pe = (t & 1) ? cosf(ang) : sinf(ang);
    float v = tok[(size_t)row*H_ + t] + pe;
    trbf[(size_t)row*H_ + t] = f2bu(v);
    float p0 = qkvec[t]*v, p1 = qkvec[H_+t]*v, p2 = qkvec[2*H_+t]*v, p3 = qkvec[3*H_+t]*v;
    const int l = t & 63, wv_ = t >> 6;
    #pragma unroll
    for (int m = 1; m < 64; m <<= 1) {
      p0 += __shfl_xor(p0, m); p1 += __shfl_xor(p1, m);
      p2 += __shfl_xor(p2, m); p3 += __shfl_xor(p3, m);
    }
    if (l == 0) { red[wv_][0]=p0; red[wv_][1]=p1; red[wv_][2]=p2; red[wv_][3]=p3; }
    __syncthreads();
    if (t < 4)
      lt[row*NH_ + t] = (red[0][t]+red[1][t]+red[2][t]+red[3][t] + qb[t]) * 0.125f;
  } else if (blk < 3072) {
    int idx = (blk - 2048)*256 + t;
    int n = idx >> 8, k = idx & 255;
    w1t[idx] = f2bu(w1[(size_t)k*FF_ + n]);
  } else if (blk < 4096) {
    int idx = (blk - 3072)*256 + t;
    int n = idx >> 10, k = idx & 1023;
    w2t[idx] = f2bu(w2[(size_t)k*H_ + n]);
  } else if (blk < 4352) {
    __shared__ float wo_s[H_];
    const int i = blk - 4096;
    wo_s[t] = wo[(size_t)i*H_ + t];
    __syncthreads();
    #pragma unroll
    for (int h = 0; h < NH_; ++h) {
      float s = 0.f;
      #pragma unroll 8
      for (int d = 0; d < 64; ++d)
        s += wo_s[h*64 + d] * wv[(size_t)(h*64 + d)*H_ + t];
      wct[(size_t)i*1024 + h*H_ + t] = f2bu(s);
    }
  } else {
    __shared__ float bv_s[H_];
    bv_s[t] = bqkv[2*H_ + t];
    __syncthreads();
    float acc = bo[t] + dq[t];
    const float4* wr = (const float4*)(wo + (size_t)t*H_);
    #pragma unroll 8
    for (int c = 0; c < 64; ++c) {
      float4 u = wr[c];
      acc += u.x*bv_s[c*4] + u.y*bv_s[c*4+1] + u.z*bv_s[c*4+2] + u.w*bv_s[c*4+3];
    }
    zbias[t] = acc;
  }
}

// ---- pool kernel: one wave per span (measured ~5.1 TB/s, HBM-optimal) ----
__global__ __launch_bounds__(256) void pool_kernel(
    const unsigned short* __restrict__ trbf,
    const float* __restrict__ lt,
    const int* __restrict__ span_ids, const int* __restrict__ span_masks,
    int span0, unsigned short* __restrict__ pooled)
{
  const int t = threadIdx.x;
  const int l = t & 63;
  const int wv = t >> 6;
  const int spanL = blockIdx.x * 4 + wv;
  const int span  = span0 + spanL;
  const int b  = span >> 13;
  const int st = span_ids[span*2];
  const int en = span_ids[span*2 + 1];
  const int len = span_masks[span] ? (en - st) : 0;

  const int h = l >> 4, w = l & 15;
  int pos = st + w; pos = pos < 0 ? 0 : (pos > S_-1 ? S_-1 : pos);
  float logit = (w < len) ? lt[(b*S_ + pos)*NH_ + h] : NEGV;
  float mx = logit;
  mx = fmaxf(mx, __shfl_xor(mx, 1));
  mx = fmaxf(mx, __shfl_xor(mx, 2));
  mx = fmaxf(mx, __shfl_xor(mx, 4));
  mx = fmaxf(mx, __shfl_xor(mx, 8));
  float e = expf(logit - mx);
  float se = e;
  se += __shfl_xor(se, 1); se += __shfl_xor(se, 2);
  se += __shfl_xor(se, 4); se += __shfl_xor(se, 8);
  const float av = e / se;

  float acc[NH_][4];
  #pragma unroll
  for (int hh = 0; hh < NH_; ++hh)
    #pragma unroll
    for (int j = 0; j < 4; ++j) acc[hh][j] = 0.f;

  const unsigned short* rb = trbf + (size_t)(b*S_)*H_ + l*4;
  #pragma unroll
  for (int w2 = 0; w2 < MAXW; ++w2) {
    int p2 = st + w2; p2 = p2 < 0 ? 0 : (p2 > S_-1 ? S_-1 : p2);
    ushort4 xv = *(const ushort4*)(rb + (size_t)p2*H_);
    float x0 = bu2f(xv.x), x1 = bu2f(xv.y), x2 = bu2f(xv.z), x3 = bu2f(xv.w);
    #pragma unroll
    for (int hh = 0; hh < NH_; ++hh) {
      float a = __shfl(av, hh*16 + w2);
      acc[hh][0] += a*x0; acc[hh][1] += a*x1;
      acc[hh][2] += a*x2; acc[hh][3] += a*x3;
    }
  }
  unsigned short* pp = pooled + (size_t)spanL * 1024;
  #pragma unroll
  for (int hh = 0; hh < NH_; ++hh) {
    ushort4 o;
    o.x = f2bu(acc[hh][0]); o.y = f2bu(acc[hh][1]);
    o.z = f2bu(acc[hh][2]); o.w = f2bu(acc[hh][3]);
    *(ushort4*)(pp + hh*256 + l*4) = o;
  }
}

// ---- K=256 GEMM step (measured no-spill at 64 arch regs): A in LDS, nf=2 mf=4 ----
__device__ __forceinline__ void gemm8(const unsigned short* __restrict__ As,
                                      const unsigned short* __restrict__ bp0,
                                      const unsigned short* __restrict__ bp1,
                                      f32x4 (&ac)[4][2], int ln16, int lg)
{
  s16x8 B0 = *(const s16x8*)bp0;
  s16x8 B1 = *(const s16x8*)bp1;
  #pragma unroll
  for (int s = 0; s < 8; ++s) {
    s16x8 N0 = B0, N1 = B1;
    if (s < 7) { N0 = *(const s16x8*)(bp0 + (s+1)*32); N1 = *(const s16x8*)(bp1 + (s+1)*32); }
    s16x8 a0 = *(const s16x8*)(As + (0*16+ln16)*LDSK + s*32 + lg*8);
    s16x8 a1 = *(const s16x8*)(As + (1*16+ln16)*LDSK + s*32 + lg*8);
    s16x8 a2 = *(const s16x8*)(As + (2*16+ln16)*LDSK + s*32 + lg*8);
    s16x8 a3 = *(const s16x8*)(As + (3*16+ln16)*LDSK + s*32 + lg*8);
    ac[0][0]=MFMA(a0,B0,ac[0][0]); ac[1][0]=MFMA(a1,B0,ac[1][0]);
    ac[2][0]=MFMA(a2,B0,ac[2][0]); ac[3][0]=MFMA(a3,B0,ac[3][0]);
    ac[0][1]=MFMA(a0,B1,ac[0][1]); ac[1][1]=MFMA(a1,B1,ac[1][1]);
    ac[2][1]=MFMA(a2,B1,ac[2][1]); ac[3][1]=MFMA(a3,B1,ac[3][1]);
    B0 = N0; B1 = N1;
  }
}

// ---- fused (measured 143us, zero spill): z = Wcomb.pooled + zbias -> LN1 -> FFN -> LN2 ----
__global__ __launch_bounds__(512, 4) void fused_gemm_kernel(
    const unsigned short* __restrict__ pooled,
    const unsigned short* __restrict__ wct,
    const float* __restrict__ zbias,
    const unsigned short* __restrict__ w1t, const float* __restrict__ b1,
    const unsigned short* __restrict__ w2t, const float* __restrict__ b2,
    const float* __restrict__ lng, const float* __restrict__ lnb,
    const int* __restrict__ masks, int span0,
    float* __restrict__ out)
{
  __shared__ __align__(16) unsigned short bufA[MT][LDSK];  // Z ping / f1
  __shared__ __align__(16) unsigned short bufB[MT][LDSK];  // Z pong / y
  __shared__ float part_s[8][MT][2];

  const int t = threadIdx.x;            // 0..511
  const int l = t & 63;
  const int w = t >> 6;                 // wave 0..7
  const int ln16 = l & 15;
  const int lg = l >> 4;
  const int m0l = blockIdx.x * MT;
  const int m0g = span0 + m0l;
  const int ncol = w * 32;

  int srow[4], k8[4];
  #pragma unroll
  for (int q = 0; q < 4; ++q) {
    int idx = q*512 + t;
    srow[q] = idx >> 5;
    k8[q]   = (idx & 31)*8;
  }
  const unsigned short* pbase = pooled + (size_t)m0l*1024;

  // ---- Z GEMM (K=1024): A staged in LDS chunks, B reg-prefetched ----
  f32x4 acc[4][2];
  #pragma unroll
  for (int mf = 0; mf < 4; ++mf){ acc[mf][0]=(f32x4){0,0,0,0}; acc[mf][1]=(f32x4){0,0,0,0}; }

  const unsigned short* bz0 = wct + (size_t)(ncol + ln16)*1024 + lg*8;
  const unsigned short* bz1 = wct + (size_t)(ncol + 16 + ln16)*1024 + lg*8;

  unsigned short* As = &bufA[0][0];
  unsigned short* An = &bufB[0][0];

  uint4 sr[4];
  #pragma unroll
  for (int q = 0; q < 4; ++q)
    sr[q] = *(const uint4*)(pbase + (size_t)srow[q]*1024 + k8[q]);
  #pragma unroll
  for (int q = 0; q < 4; ++q)
    *(uint4*)(As + srow[q]*LDSK + k8[q]) = sr[q];
  __syncthreads();

  s16x8 GA[4], GB[4];
  #define LOADBZ(G, kkg) { \
    G[0] = *(const s16x8*)(bz0 + (kkg)*64);      \
    G[1] = *(const s16x8*)(bz0 + (kkg)*64 + 32); \
    G[2] = *(const s16x8*)(bz1 + (kkg)*64);      \
    G[3] = *(const s16x8*)(bz1 + (kkg)*64 + 32); }
  LOADBZ(GA, 0); LOADBZ(GB, 1);

  auto zstep = [&](s16x8 (&G)[4], int kk, int kkgnext) {
    #pragma unroll
    for (int half = 0; half < 2; ++half) {
      s16x8 a0 = *(const s16x8*)(As + (0*16+ln16)*LDSK + kk*64 + half*32 + lg*8);
      s16x8 a1 = *(const s16x8*)(As + (1*16+ln16)*LDSK + kk*64 + half*32 + lg*8);
      s16x8 a2 = *(const s16x8*)(As + (2*16+ln16)*LDSK + kk*64 + half*32 + lg*8);
      s16x8 a3 = *(const s16x8*)(As + (3*16+ln16)*LDSK + kk*64 + half*32 + lg*8);
      acc[0][0]=MFMA(a0,G[0+half],acc[0][0]); acc[1][0]=MFMA(a1,G[0+half],acc[1][0]);
      acc[2][0]=MFMA(a2,G[0+half],acc[2][0]); acc[3][0]=MFMA(a3,G[0+half],acc[3][0]);
      acc[0][1]=MFMA(a0,G[2+half],acc[0][1]); acc[1][1]=MFMA(a1,G[2+half],acc[1][1]);
      acc[2][1]=MFMA(a2,G[2+half],acc[2][1]); acc[3][1]=MFMA(a3,G[2+half],acc[3][1]);
    }
    if (kkgnext < 16) LOADBZ(G, kkgnext);
  };

  #pragma unroll
  for (int c = 0; c < 4; ++c) {
    if (c < 3) {
      #pragma unroll
      for (int q = 0; q < 4; ++q)
        sr[q] = *(const uint4*)(pbase + (size_t)srow[q]*1024 + (c+1)*256 + k8[q]);
    }
    zstep(GA, 0, c*4 + 2);
    zstep(GB, 1, c*4 + 3);
    zstep(GA, 2, c*4 + 4);
    zstep(GB, 3, c*4 + 5);
    if (c < 3) {
      #pragma unroll
      for (int q = 0; q < 4; ++q)
        *(uint4*)(An + srow[q]*LDSK + k8[q]) = sr[q];
      __syncthreads();
      unsigned short* tmp = As; As = An; An = tmp;
    }
  }
  #undef LOADBZ

  // ---- + zbias, LN1 -> y into bufB ----
  unsigned short* y_s  = &bufB[0][0];
  unsigned short* f1_s = &bufA[0][0];
  {
    const float zb0 = zbias[ncol + ln16],      zb1 = zbias[ncol + 16 + ln16];
    const float g0  = lng[ncol + ln16],        g1  = lng[ncol + 16 + ln16];
    const float bl0 = lnb[ncol + ln16],        bl1 = lnb[ncol + 16 + ln16];
    float vals[4][4][2];
    #pragma unroll
    for (int mf = 0; mf < 4; ++mf)
      #pragma unroll
      for (int r = 0; r < 4; ++r) {
        const int row = mf*16 + lg*4 + r;
        float v0 = acc[mf][0][r] + zb0;
        float v1 = acc[mf][1][r] + zb1;
        vals[mf][r][0] = v0; vals[mf][r][1] = v1;
        float s1 = v0 + v1, s2 = v0*v0 + v1*v1;
        s1 += __shfl_xor(s1,1); s2 += __shfl_xor(s2,1);
        s1 += __shfl_xor(s1,2); s2 += __shfl_xor(s2,2);
        s1 += __shfl_xor(s1,4); s2 += __shfl_xor(s2,4);
        s1 += __shfl_xor(s1,8); s2 += __shfl_xor(s2,8);
        if (ln16 == 0) { part_s[w][row][0] = s1; part_s[w][row][1] = s2; }
      }
    __syncthreads();
    #pragma unroll
    for (int mf = 0; mf < 4; ++mf)
      #pragma unroll
      for (int r = 0; r < 4; ++r) {
        const int row = mf*16 + lg*4 + r;
        float s1 = 0.f, s2 = 0.f;
        #pragma unroll
        for (int j = 0; j < 8; ++j) { s1 += part_s[j][row][0]; s2 += part_s[j][row][1]; }
        float mean = s1 * (1.f/H_);
        float var  = s2 * (1.f/H_) - mean*mean; var = fmaxf(var, 0.f);
        float rstd = rsqrtf(var + 1e-5f);
        y_s[row*LDSK + ncol + ln16]      = f2bu((vals[mf][r][0]-mean)*rstd*g0 + bl0);
        y_s[row*LDSK + ncol + 16 + ln16] = f2bu((vals[mf][r][1]-mean)*rstd*g1 + bl1);
      }
  }
  __syncthreads();

  // ---- FFN ----
  f32x4 f2acc[4][2];
  #pragma unroll
  for (int mf = 0; mf < 4; ++mf){ f2acc[mf][0]=(f32x4){0,0,0,0}; f2acc[mf][1]=(f32x4){0,0,0,0}; }

  #pragma unroll 1
  for (int nc = 0; nc < 4; ++nc) {
    #pragma unroll
    for (int mf = 0; mf < 4; ++mf){ acc[mf][0]=(f32x4){0,0,0,0}; acc[mf][1]=(f32x4){0,0,0,0}; }
    const unsigned short* b10 = w1t + (size_t)(nc*256 + ncol + ln16)*256 + lg*8;
    const unsigned short* b11 = w1t + (size_t)(nc*256 + ncol + 16 + ln16)*256 + lg*8;
    gemm8(y_s, b10, b11, acc, ln16, lg);
    __syncthreads();   // prior FFN2 readers of f1_s done
    {
      const float bb0 = b1[nc*256 + ncol + ln16];
      const float bb1 = b1[nc*256 + ncol + 16 + ln16];
      #pragma unroll
      for (int mf = 0; mf < 4; ++mf)
        #pragma unroll
        for (int r = 0; r < 4; ++r) {
          const int row = mf*16 + lg*4 + r;
          f1_s[row*LDSK + ncol + ln16]      = f2bu(fmaxf(acc[mf][0][r] + bb0, 0.f));
          f1_s[row*LDSK + ncol + 16 + ln16] = f2bu(fmaxf(acc[mf][1][r] + bb1, 0.f));
        }
    }
    __syncthreads();
    const unsigned short* b20 = w2t + (size_t)(ncol + ln16)*1024 + nc*256 + lg*8;
    const unsigned short* b21 = w2t + (size_t)(ncol + 16 + ln16)*1024 + nc*256 + lg*8;
    gemm8(f1_s, b20, b21, f2acc, ln16, lg);
  }

  // ---- epilogue: +b2 +resid(y), LN2, mask, store ----
  {
    const float b20v = b2[ncol + ln16],   b21v = b2[ncol + 16 + ln16];
    const float g0   = lng[ncol + ln16],  g1   = lng[ncol + 16 + ln16];
    const float bl0  = lnb[ncol + ln16],  bl1  = lnb[ncol + 16 + ln16];
    float vals[4][4][2];
    #pragma unroll
    for (int mf = 0; mf < 4; ++mf)
      #pragma unroll
      for (int r = 0; r < 4; ++r) {
        const int row = mf*16 + lg*4 + r;
        float v0 = f2acc[mf][0][r] + b20v + bu2f(y_s[row*LDSK + ncol + ln16]);
        float v1 = f2acc[mf][1][r] + b21v + bu2f(y_s[row*LDSK + ncol + 16 + ln16]);
        vals[mf][r][0] = v0; vals[mf][r][1] = v1;
        float s1 = v0 + v1, s2 = v0*v0 + v1*v1;
        s1 += __shfl_xor(s1,1); s2 += __shfl_xor(s2,1);
        s1 += __shfl_xor(s1,2); s2 += __shfl_xor(s2,2);
        s1 += __shfl_xor(s1,4); s2 += __shfl_xor(s2,4);
        s1 += __shfl_xor(s1,8); s2 += __shfl_xor(s2,8);
        if (ln16 == 0) { part_s[w][row][0] = s1; part_s[w][row][1] = s2; }
      }
    __syncthreads();
    #pragma unroll
    for (int mf = 0; mf < 4; ++mf)
      #pragma unroll
      for (int r = 0; r < 4; ++r) {
        const int row = mf*16 + lg*4 + r;
        const int span = m0g + row;
        float s1 = 0.f, s2 = 0.f;
        #pragma unroll
        for (int j = 0; j < 8; ++j) { s1 += part_s[j][row][0]; s2 += part_s[j][row][1]; }
        float mean = s1 * (1.f/H_);
        float var  = s2 * (1.f/H_) - mean*mean; var = fmaxf(var, 0.f);
        float rstd = rsqrtf(var + 1e-5f);
        int mk = masks[span];
        float o0 = (vals[mf][r][0]-mean)*rstd*g0 + bl0;
        float o1 = (vals[mf][r][1]-mean)*rstd*g1 + bl1;
        out[(size_t)span*H_ + ncol + ln16]      = mk ? o0 : 0.f;
        out[(size_t)span*H_ + ncol + 16 + ln16] = mk ? o1 : 0.f;
      }
  }
}

extern "C" void kernel_launch(void* const* d_in, const int* in_sizes, int n_in,
                              void* d_out, int out_size, void* d_ws, size_t ws_size,
                              hipStream_t stream) {
  const float* tok      = (const float*)d_in[0];
  const int* span_ids   = (const int*)d_in[1];
  const int* span_masks = (const int*)d_in[2];
  const float* dq   = (const float*)d_in[4];
  const float* wq   = (const float*)d_in[5];
  const float* wk   = (const float*)d_in[6];
  const float* wv   = (const float*)d_in[7];
  const float* bqkv = (const float*)d_in[8];
  const float* wo   = (const float*)d_in[9];
  const float* bo   = (const float*)d_in[10];
  const float* lng  = (const float*)d_in[11];
  const float* lnb  = (const float*)d_in[12];
  const float* w1   = (const float*)d_in[13];
  const float* b1   = (const float*)d_in[14];
  const float* w2   = (const float*)d_in[15];
  const float* b2   = (const float*)d_in[16];

  float* ws    = (float*)d_ws;
  float* qkvec = ws;                         // 1024 f
  float* qbuf  = qkvec + 1024;               // 8 f
  float* lt    = qbuf + 8;                   // 8192 f
  float* zbias = lt + 8192;                  // 256 f
  unsigned short* ub = (unsigned short*)(zbias + 256);
  unsigned short* trbf = ub;                 // 524288
  unsigned short* wct  = trbf + 524288;      // 262144
  unsigned short* w1t  = wct + 262144;       // 262144
  unsigned short* w2t  = w1t + 262144;       // 262144
  unsigned short* pooled = w2t + 262144;     // (NSPAN/nb)*1024

  const size_t fixed_bytes = (size_t)(1024 + 8 + 8192 + 256)*4
                           + (size_t)(524288 + 262144*3)*2;
  int nb = 1;
  while (nb < 16 && fixed_bytes + (size_t)(NSPAN/nb)*1024*2 > ws_size) nb <<= 1;
  const int spans_b = NSPAN / nb;

  hipLaunchKernelGGL(prep_q_kernel, dim3(NH_), dim3(256), 0, stream,
                     dq, wq, wk, bqkv, qkvec, qbuf);
  hipLaunchKernelGGL(prep_all_kernel, dim3(4353), dim3(256), 0, stream,
                     tok, qkvec, qbuf, wv, wo, bqkv, bo, dq, w1, w2,
                     trbf, lt, wct, w1t, w2t, zbias);

  for (int bi = 0; bi < nb; ++bi) {
    const int span0 = bi * spans_b;
    hipLaunchKernelGGL(pool_kernel, dim3(spans_b/4), dim3(256), 0, stream,
                       trbf, lt, span_ids, span_masks, span0, pooled);
    hipLaunchKernelGGL(fused_gemm_kernel, dim3(spans_b/MT), dim3(512), 0, stream,
                       pooled, wct, zbias, w1t, b1, w2t, b2,
                       lng, lnb, span_masks, span0, (float*)d_out);
  }
}